// Round 7
// baseline (21038.533 us; speedup 1.0000x reference)
//
#include <hip/hip_runtime.h>
#include <hip/hip_bf16.h>

// =====================================================================
// PlantLSTM R7: register-resident weights, 8-WG groups, VGPR cap fixed.
//  - R6 post-mortem: default launch_bounds heuristic capped VGPRs at 128
//    -> 208-reg weight array spilled to scratch -> 15.5GB HBM storm.
//  - Fix: 8-WG x 8-batch groups -> 104 weight VGPRs/lane (26 float4),
//    peak live ~180; __launch_bounds__(512, 2) -> 256 cap, 1 WG/CU
//    (LDS 97KB forces it anyway).
//  - Lane owns 2 gate rows (gp=lane>>5 -> gates {i,f} or {g,o}) of the
//    WG's 32 units; wave = K-slice (L0: 40 f16; L1: 32 h0 + 32 h1).
//  - x/h reads are pure wave-broadcast LDS; weights never touch LDS.
//  - 2 rendezvous/step (h0, h1), R5 counter protocol, 8 arrivals,
//    both overlapped with independent MAC work.
//  - FC1/FC2 redundant per WG (pv local); FC1 LDS reads ks-rotated on
//    both W and X (consistent) -> conflict-free.
// =====================================================================

#define TSTEPS 512

typedef _Float16 h2 __attribute__((ext_vector_type(2)));
typedef unsigned long long ull;

#if __has_builtin(__builtin_amdgcn_fdot2)
#define FDOT2(a, b, c) __builtin_amdgcn_fdot2((a), (b), (c), false)
#else
#define FDOT2(a, b, c) ((c) + (float)(a).x * (float)(b).x + (float)(a).y * (float)(b).y)
#endif
#define BC(x) __builtin_bit_cast(h2, (x))

__device__ __forceinline__ float sigm(float x) { return 1.0f / (1.0f + __expf(-x)); }
__device__ __forceinline__ float tanhf_(float x) {
    float e = __expf(2.0f * x);
    return 1.0f - 2.0f / (e + 1.0f);
}

// ---- ws layout (bytes) ----
// Weight blob: [(c*8+w)*64+l][26 float4]:
//   q 0..4  : L0 row0, K = w*40 + q*8 .. +8   (320-col: x32|h0 256|pv8|pad24)
//   q 5..9  : L0 row1
//   q 10..13: L1 h0-part row0, K = w*32 + q*8
//   q 14..17: L1 h0-part row1
//   q 18..21: L1 h1-part row0
//   q 22..25: L1 h1-part row1
// row(c,l,r) = ((l>>5)*2 + r)*256 + c*32 + (l&31)
#define WQT_OFF 0u            // 4096 lanes * 26 * 16B = 1,703,936
#define HXA_OFF 1703936u      // 32g * 2par * 8c * 64 ull = 262,144
#define HXB_OFF 1966080u
#define FLG_OFF 2228224u      // 32g * {cntA,+16w cntB} = 4,096
#define WS_NEED 2232320u

// ------------------------- prep kernel -------------------------
__device__ __forceinline__ float l0col(const float* __restrict__ Wih0,
                                       const float* __restrict__ Whh0, int row, int K) {
    if (K < 32) return Wih0[row * 72 + K];
    if (K < 288) return Whh0[row * 256 + (K - 32)];
    if (K < 296) return Wih0[row * 72 + 32 + (K - 288)];  // pv cols 32..39
    return 0.0f;
}

__global__ void prep_w(const float* __restrict__ Wih0, const float* __restrict__ Whh0,
                       const float* __restrict__ Wih1, const float* __restrict__ Whh1,
                       char* __restrict__ ws) {
    int gid = blockIdx.x * 256 + threadIdx.x;
    if (gid < 106496) {
        int q = gid % 26;
        int rest = gid / 26;
        int l = rest & 63, w = (rest >> 6) & 7, c = rest >> 9;
        int gp = l >> 5, u = l & 31;
        int r, K;
        const float* base = nullptr;  // null -> L0 path
        if (q < 10) {
            r = q / 5;
            K = w * 40 + (q % 5) * 8;
        } else if (q < 18) {
            int z = q - 10;
            r = z >> 2;
            K = w * 32 + (z & 3) * 8;
            base = Wih1;
        } else {
            int z = q - 18;
            r = z >> 2;
            K = w * 32 + (z & 3) * 8;
            base = Whh1;
        }
        int row = (gp * 2 + r) * 256 + c * 32 + u;
        float4 v;
        float* vp = (float*)&v;
#pragma unroll
        for (int e = 0; e < 4; ++e) {
            float a0, a1;
            if (base) {
                a0 = base[row * 256 + K + 2 * e];
                a1 = base[row * 256 + K + 2 * e + 1];
            } else {
                a0 = l0col(Wih0, Whh0, row, K + 2 * e);
                a1 = l0col(Wih0, Whh0, row, K + 2 * e + 1);
            }
            h2 hv;
            hv.x = (_Float16)a0;
            hv.y = (_Float16)a1;
            vp[e] = __builtin_bit_cast(float, hv);
        }
        ((float4*)ws)[gid] = v;
    } else {
        int z = gid - 106496;
        if (z < 1024) ((unsigned*)(ws + FLG_OFF))[z] = 0u;  // counters
    }
}

// ------------------------- sync helpers -------------------------
__device__ __forceinline__ void arrive(unsigned* cnt) {
    asm volatile("s_waitcnt vmcnt(0)" ::: "memory");
    __hip_atomic_fetch_add(cnt, 1u, __ATOMIC_RELAXED, __HIP_MEMORY_SCOPE_AGENT);
}
__device__ __forceinline__ void wait_cnt(unsigned* cnt, unsigned tgt) {
    while (__hip_atomic_load(cnt, __ATOMIC_RELAXED, __HIP_MEMORY_SCOPE_AGENT) < tgt)
        __builtin_amdgcn_s_sleep(1);
}
#define CBAR() asm volatile("" ::: "memory")

__device__ __forceinline__ float dot8(const float4& W, const float4& X, float s) {
    s = FDOT2(BC(W.x), BC(X.x), s);
    s = FDOT2(BC(W.y), BC(X.y), s);
    s = FDOT2(BC(W.z), BC(X.z), s);
    s = FDOT2(BC(W.w), BC(X.w), s);
    return s;
}

// ------------------------- main kernel -------------------------
__global__ __launch_bounds__(512, 2) void lstm_main(
    const float* __restrict__ x_cv, const float* __restrict__ pv_init,
    const int* __restrict__ scen, const float* __restrict__ emb_table,
    const float* __restrict__ Wih0, const float* __restrict__ b_ih0,
    const float* __restrict__ b_hh0, const float* __restrict__ b_ih1,
    const float* __restrict__ b_hh1, const float* __restrict__ fc1_w,
    const float* __restrict__ fc1_b, const float* __restrict__ fc2_w,
    const float* __restrict__ fc2_b, char* __restrict__ ws,
    float* __restrict__ out) {
    struct __align__(16) SM {
        char fc1w[4 * 16400];     // [ks]{16400}[q]{2048}[row]{16}
        char fc2w[2048];          // [jo*4+ks][16 h2]
        char xt0[8 * 640];        // [b][x32|h0 256|pv8|pad24] f16
        char xt1[8 * 1024];       // [b][h0 256|h1 256] f16
        float g0[8][128];         // [b][gate*32+u]
        float g1[8][128];
        float biasE[8][128];
        float bias1[128];
        unsigned short htmp[8][32];
        char fc1o[8 * 256];       // [b][128 f16]
        float embs[8][32];
        int scen_l[8];
    };
    __shared__ SM sm;

    const int tid = threadIdx.x;
    const int lane = tid & 63;
    const int wv = tid >> 6;
    const int c = blockIdx.x & 7;
    const int g = blockIdx.x >> 3;
    const int B0 = g * 8;
    const int gp = lane >> 5, u = lane & 31;

    ull* hxA = (ull*)(ws + HXA_OFF) + (unsigned)g * 1024u;  // [par][c][64]
    ull* hxB = (ull*)(ws + HXB_OFF) + (unsigned)g * 1024u;
    unsigned* cntA = (unsigned*)(ws + FLG_OFF) + (unsigned)g * 32u;
    unsigned* cntB = cntA + 16;

    // ---- weights -> registers (104 VGPRs, all static indexing) ----
    float4 wr[26];
    {
        const float4* wb = (const float4*)(ws + WQT_OFF) +
                           (unsigned)(((c * 8 + wv) * 64 + lane) * 26);
#pragma unroll
        for (int q = 0; q < 26; ++q) wr[q] = wb[q];
    }

    // ---- init ----
    if (tid < 8) sm.scen_l[tid] = scen[B0 + tid];
    __syncthreads();
    if (tid < 256) {
        int b = tid >> 5, e = tid & 31;
        sm.embs[b][e] = emb_table[sm.scen_l[b] * 32 + e];
    }
    for (int idx = tid; idx < 640; idx += 512) ((ull*)sm.xt0)[idx] = 0ull;
    for (int idx = tid; idx < 1024; idx += 512) ((ull*)sm.xt1)[idx] = 0ull;
    {   // FC1 weights: [ks][q][row][16B]
        int ks = tid & 3, row = tid >> 2;
        for (int q = 0; q < 8; ++q) {
            const float* src = fc1_w + row * 256 + ks * 64 + q * 8;
            char* dst = sm.fc1w + ks * 16400 + q * 2048 + row * 16;
#pragma unroll
            for (int e = 0; e < 4; ++e) {
                h2 v;
                v.x = (_Float16)src[2 * e];
                v.y = (_Float16)src[2 * e + 1];
                *(h2*)(dst + e * 4) = v;
            }
        }
    }
    if (tid < 128) {  // FC2 weights
        int jo = tid >> 4, ks = (tid >> 2) & 3, e4 = tid & 3;
        float4 v;
        float* vp = (float*)&v;
#pragma unroll
        for (int e = 0; e < 4; ++e) {
            h2 hv;
            hv.x = (_Float16)fc2_w[jo * 128 + ks * 32 + e4 * 8 + 2 * e];
            hv.y = (_Float16)fc2_w[jo * 128 + ks * 32 + e4 * 8 + 2 * e + 1];
            vp[e] = __builtin_bit_cast(float, hv);
        }
        *(float4*)(sm.fc2w + (jo * 4 + ks) * 64 + e4 * 16) = v;
    }
    if (tid < 128) {
        int row = (tid >> 5) * 256 + c * 32 + (tid & 31);
        sm.bias1[tid] = b_ih1[row] + b_hh1[row];
    }
    __syncthreads();
    for (int idx = tid; idx < 1024; idx += 512) {
        int b = idx >> 7, r = idx & 127;
        int row = (r >> 5) * 256 + c * 32 + (r & 31);
        float s = b_ih0[row] + b_hh0[row];
        for (int e = 0; e < 32; ++e) s += sm.embs[b][e] * Wih0[row * 72 + 40 + e];
        sm.biasE[b][r] = s;
    }
    if (tid < 256) {
        int b = tid >> 5, k = tid & 31;
        float xv = x_cv[((size_t)(B0 + b) * TSTEPS + 0) * 32 + k];
        *(_Float16*)(sm.xt0 + b * 640 + k * 2) = (_Float16)xv;
    }
    if (tid < 64) {
        int b = tid >> 3, jo = tid & 7;
        *(_Float16*)(sm.xt0 + b * 640 + 576 + jo * 2) = (_Float16)pv_init[(B0 + b) * 8 + jo];
    }
    __syncthreads();
    for (int idx = tid; idx < 1024; idx += 512) {
        int b = idx >> 7, r = idx & 127;
        sm.g0[b][r] = sm.biasE[b][r];
        sm.g1[b][r] = sm.bias1[r];
    }
    const int f_ks = tid & 3, f_row = tid >> 2;
    const float fc1b_r = fc1_b[f_row];
    // FC2 mapping (tid<256): ks2 = tid&3, jo=(tid>>2)&7, bo=tid>>5
    const int ks2 = tid & 3, jo = (tid >> 2) & 7, bo = tid >> 5;
    const float fc2b_r = (tid < 256) ? fc2_b[jo] : 0.0f;
    // FC1 register weights, ks-rotated on load (q' = (i + 2*ks) & 7)
    float4 f1w[8];
#pragma unroll
    for (int i = 0; i < 8; ++i) {
        int qx = (i + 2 * f_ks) & 7;
        f1w[i] = *(const float4*)(sm.fc1w + f_ks * 16400 + qx * 2048 + f_row * 16);
    }
    float c0 = 0.0f, c1 = 0.0f;
    __syncthreads();

    // ==================== time loop ====================
    for (int t = 0; t < TSTEPS; ++t) {
        const int par = t & 1;
        const unsigned tgt = 8u * (unsigned)(t + 1);

        // ---- P3: L0 gates (register weights, broadcast x) ----
        {
            float a0[8], a1[8];
#pragma unroll
            for (int b = 0; b < 8; ++b) a0[b] = a1[b] = 0.0f;
#pragma unroll
            for (int b = 0; b < 8; ++b) {
                const char* xb = sm.xt0 + b * 640 + wv * 80;
#pragma unroll
                for (int q = 0; q < 5; ++q) {
                    float4 xq = *(const float4*)(xb + q * 16);
                    a0[b] = dot8(wr[q], xq, a0[b]);
                    a1[b] = dot8(wr[5 + q], xq, a1[b]);
                }
            }
#pragma unroll
            for (int b = 0; b < 8; ++b) {
                atomicAdd(&sm.g0[b][gp * 64 + u], a0[b]);
                atomicAdd(&sm.g0[b][gp * 64 + 32 + u], a1[b]);
            }
        }
        __syncthreads();  // B1

        // ---- P4: cell 0 ----
        if (tid < 256) {
            int uu = tid & 31, b = tid >> 5;
            float gi = sm.g0[b][uu], gf = sm.g0[b][32 + uu];
            float gc = sm.g0[b][64 + uu], go = sm.g0[b][96 + uu];
            c0 = sigm(gf) * c0 + sigm(gi) * tanhf_(gc);
            sm.htmp[b][uu] = __builtin_bit_cast(unsigned short, (_Float16)(sigm(go) * tanhf_(c0)));
        }
        __syncthreads();  // B2

        // ---- P5: post h0; L1 h1(t-1)-half; g0 reinit; wait ----
        float e0[8], e1[8];
        if (wv == 0) {
            ull v = ((const ull*)sm.htmp)[lane];  // lane = b*8+e
            __hip_atomic_store(&hxA[(par * 8 + c) * 64 + lane], v, __ATOMIC_RELAXED,
                               __HIP_MEMORY_SCOPE_AGENT);
            if (lane == 0) arrive(cntA);
        }
        {
#pragma unroll
            for (int b = 0; b < 8; ++b) e0[b] = e1[b] = 0.0f;
#pragma unroll
            for (int b = 0; b < 8; ++b) {
                const char* xb = sm.xt1 + b * 1024 + 512 + wv * 64;
#pragma unroll
                for (int q = 0; q < 4; ++q) {
                    float4 xq = *(const float4*)(xb + q * 16);
                    e0[b] = dot8(wr[18 + q], xq, e0[b]);
                    e1[b] = dot8(wr[22 + q], xq, e1[b]);
                }
            }
        }
        for (int idx = tid; idx < 1024; idx += 512) {
            int b = idx >> 7, r = idx & 127;
            sm.g0[b][r] = sm.biasE[b][r];
        }
        if (tid == 0) wait_cnt(cntA, tgt);
        __syncthreads();  // B3
        CBAR();

        // ---- P6: gather h0 -> xt1[h0], xt0[h0] ----
        {
            int cc = tid >> 6, l = tid & 63;
            ull v = __hip_atomic_load(&hxA[(par * 8 + cc) * 64 + l], __ATOMIC_RELAXED,
                                      __HIP_MEMORY_SCOPE_AGENT);
            int b = l >> 3, u4 = cc * 32 + (l & 7) * 4;
            *(ull*)(sm.xt1 + b * 1024 + u4 * 2) = v;
            *(ull*)(sm.xt0 + b * 640 + 64 + u4 * 2) = v;
        }
        __syncthreads();  // B4

        // ---- P7: L1 h0-half + commit both halves ----
        {
#pragma unroll
            for (int b = 0; b < 8; ++b) {
                const char* xb = sm.xt1 + b * 1024 + wv * 64;
#pragma unroll
                for (int q = 0; q < 4; ++q) {
                    float4 xq = *(const float4*)(xb + q * 16);
                    e0[b] = dot8(wr[10 + q], xq, e0[b]);
                    e1[b] = dot8(wr[14 + q], xq, e1[b]);
                }
            }
#pragma unroll
            for (int b = 0; b < 8; ++b) {
                atomicAdd(&sm.g1[b][gp * 64 + u], e0[b]);
                atomicAdd(&sm.g1[b][gp * 64 + 32 + u], e1[b]);
            }
        }
        __syncthreads();  // B5

        // ---- P8: cell 1 ----
        if (tid < 256) {
            int uu = tid & 31, b = tid >> 5;
            float gi = sm.g1[b][uu], gf = sm.g1[b][32 + uu];
            float gc = sm.g1[b][64 + uu], go = sm.g1[b][96 + uu];
            c1 = sigm(gf) * c1 + sigm(gi) * tanhf_(gc);
            sm.htmp[b][uu] = __builtin_bit_cast(unsigned short, (_Float16)(sigm(go) * tanhf_(c1)));
        }
        __syncthreads();  // B6

        // ---- P9: post h1; stage x(t+1); g1 reinit; wait ----
        if (wv == 0) {
            ull v = ((const ull*)sm.htmp)[lane];
            __hip_atomic_store(&hxB[(par * 8 + c) * 64 + lane], v, __ATOMIC_RELAXED,
                               __HIP_MEMORY_SCOPE_AGENT);
            if (lane == 0) arrive(cntB);
        }
        if (tid >= 256 && t + 1 < TSTEPS) {
            int tt = tid - 256;
            int b = tt >> 5, k = tt & 31;
            float xv = x_cv[((size_t)(B0 + b) * TSTEPS + t + 1) * 32 + k];
            *(_Float16*)(sm.xt0 + b * 640 + k * 2) = (_Float16)xv;
        }
        for (int idx = tid; idx < 1024; idx += 512) {
            int b = idx >> 7, r = idx & 127;
            sm.g1[b][r] = sm.bias1[r];
        }
        if (tid == 0) wait_cnt(cntB, tgt);
        __syncthreads();  // B7
        CBAR();

        // ---- P10: gather h1 -> xt1[h1] ----
        {
            int cc = tid >> 6, l = tid & 63;
            ull v = __hip_atomic_load(&hxB[(par * 8 + cc) * 64 + l], __ATOMIC_RELAXED,
                                      __HIP_MEMORY_SCOPE_AGENT);
            int b = l >> 3, u4 = cc * 32 + (l & 7) * 4;
            *(ull*)(sm.xt1 + b * 1024 + 512 + u4 * 2) = v;
        }
        __syncthreads();  // B8

        // ---- P1: FC1 all 8 batches (redundant; ks-rotated reads) ----
        {
#pragma unroll
            for (int b = 0; b < 8; ++b) {
                float a = 0.0f;
                const char* xb = sm.xt1 + b * 1024 + 512 + f_ks * 128;
#pragma unroll
                for (int i = 0; i < 8; ++i) {
                    int qx = (i + 2 * f_ks) & 7;
                    a = dot8(f1w[i], *(const float4*)(xb + qx * 16), a);
                }
                a += __shfl_xor(a, 1);
                a += __shfl_xor(a, 2);
                if (f_ks == 0) {
                    float r = fmaxf(a + fc1b_r, 0.0f);
                    *(unsigned short*)(sm.fc1o + b * 256 + f_row * 2) =
                        __builtin_bit_cast(unsigned short, (_Float16)r);
                }
            }
        }
        __syncthreads();  // B9

        // ---- P2: FC2 -> pv (local) + out (c==0) ----
        if (tid < 256) {
            const char* wb2 = sm.fc2w + (jo * 4 + ks2) * 64;
            const char* xb2 = sm.fc1o + bo * 256 + ks2 * 64;
            float s = 0.0f;
#pragma unroll
            for (int q = 0; q < 4; ++q)
                s = dot8(*(const float4*)(wb2 + q * 16), *(const float4*)(xb2 + q * 16), s);
            s += __shfl_xor(s, 1);
            s += __shfl_xor(s, 2);
            if (ks2 == 0) {
                float pv = s + fc2b_r;
                *(_Float16*)(sm.xt0 + bo * 640 + 576 + jo * 2) = (_Float16)pv;
                if (c == 0) out[((size_t)(B0 + bo) * TSTEPS + t) * 8 + jo] = pv;
            }
        }
        __syncthreads();  // B10
    }
}

// ------------------------- launch -------------------------
extern "C" void kernel_launch(void* const* d_in, const int* in_sizes, int n_in,
                              void* d_out, int out_size, void* d_ws, size_t ws_size,
                              hipStream_t stream) {
    if (ws_size < WS_NEED) return;

    const float* x_cv = (const float*)d_in[0];
    const float* pv_init = (const float*)d_in[1];
    const int* scen = (const int*)d_in[2];
    const float* embt = (const float*)d_in[3];
    const float* Wih0 = (const float*)d_in[4];
    const float* Whh0 = (const float*)d_in[5];
    const float* bih0 = (const float*)d_in[6];
    const float* bhh0 = (const float*)d_in[7];
    const float* Wih1 = (const float*)d_in[8];
    const float* Whh1 = (const float*)d_in[9];
    const float* bih1 = (const float*)d_in[10];
    const float* bhh1 = (const float*)d_in[11];
    const float* fc1w = (const float*)d_in[12];
    const float* fc1b = (const float*)d_in[13];
    const float* fc2w = (const float*)d_in[14];
    const float* fc2b = (const float*)d_in[15];

    char* ws = (char*)d_ws;

    prep_w<<<420, 256, 0, stream>>>(Wih0, Whh0, Wih1, Whh1, ws);

    lstm_main<<<256, 512, 0, stream>>>(x_cv, pv_init, scen, embt, Wih0, bih0, bhh0,
                                       bih1, bhh1, fc1w, fc1b, fc2w, fc2b, ws,
                                       (float*)d_out);
}

// Round 8
// 21010.139 us; speedup vs baseline: 1.0014x; 1.0014x over previous
//
#include <hip/hip_runtime.h>
#include <hip/hip_bf16.h>

// =====================================================================
// PlantLSTM R8: R7 + amdgpu_waves_per_eu(1,2) — make the 104 weight
// VGPRs actually stay in registers.
//  - R6/R7 post-mortem: compiler kept a 128-VGPR cap (4 waves/EU target)
//    regardless of __launch_bounds__ 2nd arg -> wr[26] spilled to
//    scratch -> 3.7GB HBM/dispatch ≈ the entire 21ms. The native
//    attribute sets the backend's waves-per-EU range directly:
//    min=1 -> 512-VGPR budget; LDS (97KB) already caps occupancy at
//    1 block/CU (2 waves/SIMD), so no occupancy loss.
//  - Everything else identical to R7: 32 groups x 8 WGs x 8 batches,
//    register-resident LSTM weights (26 float4/lane), wave-broadcast
//    x/h reads, 2 overlapped 8-participant rendezvous per step (R5
//    counter protocol), redundant FC1/FC2 per WG (pv local),
//    ks-rotated FC1 LDS access.
// =====================================================================

#define TSTEPS 512

typedef _Float16 h2 __attribute__((ext_vector_type(2)));
typedef unsigned long long ull;

#if __has_builtin(__builtin_amdgcn_fdot2)
#define FDOT2(a, b, c) __builtin_amdgcn_fdot2((a), (b), (c), false)
#else
#define FDOT2(a, b, c) ((c) + (float)(a).x * (float)(b).x + (float)(a).y * (float)(b).y)
#endif
#define BC(x) __builtin_bit_cast(h2, (x))

__device__ __forceinline__ float sigm(float x) { return 1.0f / (1.0f + __expf(-x)); }
__device__ __forceinline__ float tanhf_(float x) {
    float e = __expf(2.0f * x);
    return 1.0f - 2.0f / (e + 1.0f);
}

// ---- ws layout (bytes) ----
// Weight blob: [(c*8+w)*64+l][26 float4]:
//   q 0..4  : L0 row0, K = w*40 + q*8 .. +8   (320-col: x32|h0 256|pv8|pad24)
//   q 5..9  : L0 row1
//   q 10..13: L1 h0-part row0, K = w*32 + q*8
//   q 14..17: L1 h0-part row1
//   q 18..21: L1 h1-part row0
//   q 22..25: L1 h1-part row1
// row(c,l,r) = ((l>>5)*2 + r)*256 + c*32 + (l&31)
#define WQT_OFF 0u            // 4096 lanes * 26 * 16B = 1,703,936
#define HXA_OFF 1703936u      // 32g * 2par * 8c * 64 ull = 262,144
#define HXB_OFF 1966080u
#define FLG_OFF 2228224u      // 32g * {cntA,+16w cntB} = 4,096
#define WS_NEED 2232320u

// ------------------------- prep kernel -------------------------
__device__ __forceinline__ float l0col(const float* __restrict__ Wih0,
                                       const float* __restrict__ Whh0, int row, int K) {
    if (K < 32) return Wih0[row * 72 + K];
    if (K < 288) return Whh0[row * 256 + (K - 32)];
    if (K < 296) return Wih0[row * 72 + 32 + (K - 288)];  // pv cols 32..39
    return 0.0f;
}

__global__ void prep_w(const float* __restrict__ Wih0, const float* __restrict__ Whh0,
                       const float* __restrict__ Wih1, const float* __restrict__ Whh1,
                       char* __restrict__ ws) {
    int gid = blockIdx.x * 256 + threadIdx.x;
    if (gid < 106496) {
        int q = gid % 26;
        int rest = gid / 26;
        int l = rest & 63, w = (rest >> 6) & 7, c = rest >> 9;
        int gp = l >> 5, u = l & 31;
        int r, K;
        const float* base = nullptr;  // null -> L0 path
        if (q < 10) {
            r = q / 5;
            K = w * 40 + (q % 5) * 8;
        } else if (q < 18) {
            int z = q - 10;
            r = z >> 2;
            K = w * 32 + (z & 3) * 8;
            base = Wih1;
        } else {
            int z = q - 18;
            r = z >> 2;
            K = w * 32 + (z & 3) * 8;
            base = Whh1;
        }
        int row = (gp * 2 + r) * 256 + c * 32 + u;
        float4 v;
        float* vp = (float*)&v;
#pragma unroll
        for (int e = 0; e < 4; ++e) {
            float a0, a1;
            if (base) {
                a0 = base[row * 256 + K + 2 * e];
                a1 = base[row * 256 + K + 2 * e + 1];
            } else {
                a0 = l0col(Wih0, Whh0, row, K + 2 * e);
                a1 = l0col(Wih0, Whh0, row, K + 2 * e + 1);
            }
            h2 hv;
            hv.x = (_Float16)a0;
            hv.y = (_Float16)a1;
            vp[e] = __builtin_bit_cast(float, hv);
        }
        ((float4*)ws)[gid] = v;
    } else {
        int z = gid - 106496;
        if (z < 1024) ((unsigned*)(ws + FLG_OFF))[z] = 0u;  // counters
    }
}

// ------------------------- sync helpers -------------------------
__device__ __forceinline__ void arrive(unsigned* cnt) {
    asm volatile("s_waitcnt vmcnt(0)" ::: "memory");
    __hip_atomic_fetch_add(cnt, 1u, __ATOMIC_RELAXED, __HIP_MEMORY_SCOPE_AGENT);
}
__device__ __forceinline__ void wait_cnt(unsigned* cnt, unsigned tgt) {
    while (__hip_atomic_load(cnt, __ATOMIC_RELAXED, __HIP_MEMORY_SCOPE_AGENT) < tgt)
        __builtin_amdgcn_s_sleep(1);
}
#define CBAR() asm volatile("" ::: "memory")

__device__ __forceinline__ float dot8(const float4& W, const float4& X, float s) {
    s = FDOT2(BC(W.x), BC(X.x), s);
    s = FDOT2(BC(W.y), BC(X.y), s);
    s = FDOT2(BC(W.z), BC(X.z), s);
    s = FDOT2(BC(W.w), BC(X.w), s);
    return s;
}

// ------------------------- main kernel -------------------------
__global__ __launch_bounds__(512) __attribute__((amdgpu_waves_per_eu(1, 2)))
void lstm_main(
    const float* __restrict__ x_cv, const float* __restrict__ pv_init,
    const int* __restrict__ scen, const float* __restrict__ emb_table,
    const float* __restrict__ Wih0, const float* __restrict__ b_ih0,
    const float* __restrict__ b_hh0, const float* __restrict__ b_ih1,
    const float* __restrict__ b_hh1, const float* __restrict__ fc1_w,
    const float* __restrict__ fc1_b, const float* __restrict__ fc2_w,
    const float* __restrict__ fc2_b, char* __restrict__ ws,
    float* __restrict__ out) {
    struct __align__(16) SM {
        char fc1w[4 * 16400];     // [ks]{16400}[q]{2048}[row]{16}
        char fc2w[2048];          // [jo*4+ks][16 h2]
        char xt0[8 * 640];        // [b][x32|h0 256|pv8|pad24] f16
        char xt1[8 * 1024];       // [b][h0 256|h1 256] f16
        float g0[8][128];         // [b][gate*32+u]
        float g1[8][128];
        float biasE[8][128];
        float bias1[128];
        unsigned short htmp[8][32];
        char fc1o[8 * 256];       // [b][128 f16]
        float embs[8][32];
        int scen_l[8];
    };
    __shared__ SM sm;

    const int tid = threadIdx.x;
    const int lane = tid & 63;
    const int wv = tid >> 6;
    const int c = blockIdx.x & 7;
    const int g = blockIdx.x >> 3;
    const int B0 = g * 8;
    const int gp = lane >> 5, u = lane & 31;

    ull* hxA = (ull*)(ws + HXA_OFF) + (unsigned)g * 1024u;  // [par][c][64]
    ull* hxB = (ull*)(ws + HXB_OFF) + (unsigned)g * 1024u;
    unsigned* cntA = (unsigned*)(ws + FLG_OFF) + (unsigned)g * 32u;
    unsigned* cntB = cntA + 16;

    // ---- weights -> registers (104 VGPRs, all static indexing) ----
    float4 wr[26];
    {
        const float4* wb = (const float4*)(ws + WQT_OFF) +
                           (unsigned)(((c * 8 + wv) * 64 + lane) * 26);
#pragma unroll
        for (int q = 0; q < 26; ++q) wr[q] = wb[q];
    }

    // ---- init ----
    if (tid < 8) sm.scen_l[tid] = scen[B0 + tid];
    __syncthreads();
    if (tid < 256) {
        int b = tid >> 5, e = tid & 31;
        sm.embs[b][e] = emb_table[sm.scen_l[b] * 32 + e];
    }
    for (int idx = tid; idx < 640; idx += 512) ((ull*)sm.xt0)[idx] = 0ull;
    for (int idx = tid; idx < 1024; idx += 512) ((ull*)sm.xt1)[idx] = 0ull;
    {   // FC1 weights: [ks][q][row][16B]
        int ks = tid & 3, row = tid >> 2;
        for (int q = 0; q < 8; ++q) {
            const float* src = fc1_w + row * 256 + ks * 64 + q * 8;
            char* dst = sm.fc1w + ks * 16400 + q * 2048 + row * 16;
#pragma unroll
            for (int e = 0; e < 4; ++e) {
                h2 v;
                v.x = (_Float16)src[2 * e];
                v.y = (_Float16)src[2 * e + 1];
                *(h2*)(dst + e * 4) = v;
            }
        }
    }
    if (tid < 128) {  // FC2 weights
        int jo = tid >> 4, ks = (tid >> 2) & 3, e4 = tid & 3;
        float4 v;
        float* vp = (float*)&v;
#pragma unroll
        for (int e = 0; e < 4; ++e) {
            h2 hv;
            hv.x = (_Float16)fc2_w[jo * 128 + ks * 32 + e4 * 8 + 2 * e];
            hv.y = (_Float16)fc2_w[jo * 128 + ks * 32 + e4 * 8 + 2 * e + 1];
            vp[e] = __builtin_bit_cast(float, hv);
        }
        *(float4*)(sm.fc2w + (jo * 4 + ks) * 64 + e4 * 16) = v;
    }
    if (tid < 128) {
        int row = (tid >> 5) * 256 + c * 32 + (tid & 31);
        sm.bias1[tid] = b_ih1[row] + b_hh1[row];
    }
    __syncthreads();
    for (int idx = tid; idx < 1024; idx += 512) {
        int b = idx >> 7, r = idx & 127;
        int row = (r >> 5) * 256 + c * 32 + (r & 31);
        float s = b_ih0[row] + b_hh0[row];
        for (int e = 0; e < 32; ++e) s += sm.embs[b][e] * Wih0[row * 72 + 40 + e];
        sm.biasE[b][r] = s;
    }
    if (tid < 256) {
        int b = tid >> 5, k = tid & 31;
        float xv = x_cv[((size_t)(B0 + b) * TSTEPS + 0) * 32 + k];
        *(_Float16*)(sm.xt0 + b * 640 + k * 2) = (_Float16)xv;
    }
    if (tid < 64) {
        int b = tid >> 3, jo = tid & 7;
        *(_Float16*)(sm.xt0 + b * 640 + 576 + jo * 2) = (_Float16)pv_init[(B0 + b) * 8 + jo];
    }
    __syncthreads();
    for (int idx = tid; idx < 1024; idx += 512) {
        int b = idx >> 7, r = idx & 127;
        sm.g0[b][r] = sm.biasE[b][r];
        sm.g1[b][r] = sm.bias1[r];
    }
    const int f_ks = tid & 3, f_row = tid >> 2;
    const float fc1b_r = fc1_b[f_row];
    // FC2 mapping (tid<256): ks2 = tid&3, jo=(tid>>2)&7, bo=tid>>5
    const int ks2 = tid & 3, jo = (tid >> 2) & 7, bo = tid >> 5;
    const float fc2b_r = (tid < 256) ? fc2_b[jo] : 0.0f;
    // FC1 register weights, ks-rotated on load (q' = (i + 2*ks) & 7)
    float4 f1w[8];
#pragma unroll
    for (int i = 0; i < 8; ++i) {
        int qx = (i + 2 * f_ks) & 7;
        f1w[i] = *(const float4*)(sm.fc1w + f_ks * 16400 + qx * 2048 + f_row * 16);
    }
    float c0 = 0.0f, c1 = 0.0f;
    __syncthreads();

    // ==================== time loop ====================
    for (int t = 0; t < TSTEPS; ++t) {
        const int par = t & 1;
        const unsigned tgt = 8u * (unsigned)(t + 1);

        // ---- P3: L0 gates (register weights, broadcast x) ----
        {
            float a0[8], a1[8];
#pragma unroll
            for (int b = 0; b < 8; ++b) a0[b] = a1[b] = 0.0f;
#pragma unroll
            for (int b = 0; b < 8; ++b) {
                const char* xb = sm.xt0 + b * 640 + wv * 80;
#pragma unroll
                for (int q = 0; q < 5; ++q) {
                    float4 xq = *(const float4*)(xb + q * 16);
                    a0[b] = dot8(wr[q], xq, a0[b]);
                    a1[b] = dot8(wr[5 + q], xq, a1[b]);
                }
            }
#pragma unroll
            for (int b = 0; b < 8; ++b) {
                atomicAdd(&sm.g0[b][gp * 64 + u], a0[b]);
                atomicAdd(&sm.g0[b][gp * 64 + 32 + u], a1[b]);
            }
        }
        __syncthreads();  // B1

        // ---- P4: cell 0 ----
        if (tid < 256) {
            int uu = tid & 31, b = tid >> 5;
            float gi = sm.g0[b][uu], gf = sm.g0[b][32 + uu];
            float gc = sm.g0[b][64 + uu], go = sm.g0[b][96 + uu];
            c0 = sigm(gf) * c0 + sigm(gi) * tanhf_(gc);
            sm.htmp[b][uu] = __builtin_bit_cast(unsigned short, (_Float16)(sigm(go) * tanhf_(c0)));
        }
        __syncthreads();  // B2

        // ---- P5: post h0; L1 h1(t-1)-half; g0 reinit; wait ----
        float e0[8], e1[8];
        if (wv == 0) {
            ull v = ((const ull*)sm.htmp)[lane];  // lane = b*8+e
            __hip_atomic_store(&hxA[(par * 8 + c) * 64 + lane], v, __ATOMIC_RELAXED,
                               __HIP_MEMORY_SCOPE_AGENT);
            if (lane == 0) arrive(cntA);
        }
        {
#pragma unroll
            for (int b = 0; b < 8; ++b) e0[b] = e1[b] = 0.0f;
#pragma unroll
            for (int b = 0; b < 8; ++b) {
                const char* xb = sm.xt1 + b * 1024 + 512 + wv * 64;
#pragma unroll
                for (int q = 0; q < 4; ++q) {
                    float4 xq = *(const float4*)(xb + q * 16);
                    e0[b] = dot8(wr[18 + q], xq, e0[b]);
                    e1[b] = dot8(wr[22 + q], xq, e1[b]);
                }
            }
        }
        for (int idx = tid; idx < 1024; idx += 512) {
            int b = idx >> 7, r = idx & 127;
            sm.g0[b][r] = sm.biasE[b][r];
        }
        if (tid == 0) wait_cnt(cntA, tgt);
        __syncthreads();  // B3
        CBAR();

        // ---- P6: gather h0 -> xt1[h0], xt0[h0] ----
        {
            int cc = tid >> 6, l = tid & 63;
            ull v = __hip_atomic_load(&hxA[(par * 8 + cc) * 64 + l], __ATOMIC_RELAXED,
                                      __HIP_MEMORY_SCOPE_AGENT);
            int b = l >> 3, u4 = cc * 32 + (l & 7) * 4;
            *(ull*)(sm.xt1 + b * 1024 + u4 * 2) = v;
            *(ull*)(sm.xt0 + b * 640 + 64 + u4 * 2) = v;
        }
        __syncthreads();  // B4

        // ---- P7: L1 h0-half + commit both halves ----
        {
#pragma unroll
            for (int b = 0; b < 8; ++b) {
                const char* xb = sm.xt1 + b * 1024 + wv * 64;
#pragma unroll
                for (int q = 0; q < 4; ++q) {
                    float4 xq = *(const float4*)(xb + q * 16);
                    e0[b] = dot8(wr[10 + q], xq, e0[b]);
                    e1[b] = dot8(wr[14 + q], xq, e1[b]);
                }
            }
#pragma unroll
            for (int b = 0; b < 8; ++b) {
                atomicAdd(&sm.g1[b][gp * 64 + u], e0[b]);
                atomicAdd(&sm.g1[b][gp * 64 + 32 + u], e1[b]);
            }
        }
        __syncthreads();  // B5

        // ---- P8: cell 1 ----
        if (tid < 256) {
            int uu = tid & 31, b = tid >> 5;
            float gi = sm.g1[b][uu], gf = sm.g1[b][32 + uu];
            float gc = sm.g1[b][64 + uu], go = sm.g1[b][96 + uu];
            c1 = sigm(gf) * c1 + sigm(gi) * tanhf_(gc);
            sm.htmp[b][uu] = __builtin_bit_cast(unsigned short, (_Float16)(sigm(go) * tanhf_(c1)));
        }
        __syncthreads();  // B6

        // ---- P9: post h1; stage x(t+1); g1 reinit; wait ----
        if (wv == 0) {
            ull v = ((const ull*)sm.htmp)[lane];
            __hip_atomic_store(&hxB[(par * 8 + c) * 64 + lane], v, __ATOMIC_RELAXED,
                               __HIP_MEMORY_SCOPE_AGENT);
            if (lane == 0) arrive(cntB);
        }
        if (tid >= 256 && t + 1 < TSTEPS) {
            int tt = tid - 256;
            int b = tt >> 5, k = tt & 31;
            float xv = x_cv[((size_t)(B0 + b) * TSTEPS + t + 1) * 32 + k];
            *(_Float16*)(sm.xt0 + b * 640 + k * 2) = (_Float16)xv;
        }
        for (int idx = tid; idx < 1024; idx += 512) {
            int b = idx >> 7, r = idx & 127;
            sm.g1[b][r] = sm.bias1[r];
        }
        if (tid == 0) wait_cnt(cntB, tgt);
        __syncthreads();  // B7
        CBAR();

        // ---- P10: gather h1 -> xt1[h1] ----
        {
            int cc = tid >> 6, l = tid & 63;
            ull v = __hip_atomic_load(&hxB[(par * 8 + cc) * 64 + l], __ATOMIC_RELAXED,
                                      __HIP_MEMORY_SCOPE_AGENT);
            int b = l >> 3, u4 = cc * 32 + (l & 7) * 4;
            *(ull*)(sm.xt1 + b * 1024 + 512 + u4 * 2) = v;
        }
        __syncthreads();  // B8

        // ---- P1: FC1 all 8 batches (redundant; ks-rotated reads) ----
        {
#pragma unroll
            for (int b = 0; b < 8; ++b) {
                float a = 0.0f;
                const char* xb = sm.xt1 + b * 1024 + 512 + f_ks * 128;
#pragma unroll
                for (int i = 0; i < 8; ++i) {
                    int qx = (i + 2 * f_ks) & 7;
                    a = dot8(f1w[i], *(const float4*)(xb + qx * 16), a);
                }
                a += __shfl_xor(a, 1);
                a += __shfl_xor(a, 2);
                if (f_ks == 0) {
                    float r = fmaxf(a + fc1b_r, 0.0f);
                    *(unsigned short*)(sm.fc1o + b * 256 + f_row * 2) =
                        __builtin_bit_cast(unsigned short, (_Float16)r);
                }
            }
        }
        __syncthreads();  // B9

        // ---- P2: FC2 -> pv (local) + out (c==0) ----
        if (tid < 256) {
            const char* wb2 = sm.fc2w + (jo * 4 + ks2) * 64;
            const char* xb2 = sm.fc1o + bo * 256 + ks2 * 64;
            float s = 0.0f;
#pragma unroll
            for (int q = 0; q < 4; ++q)
                s = dot8(*(const float4*)(wb2 + q * 16), *(const float4*)(xb2 + q * 16), s);
            s += __shfl_xor(s, 1);
            s += __shfl_xor(s, 2);
            if (ks2 == 0) {
                float pv = s + fc2b_r;
                *(_Float16*)(sm.xt0 + bo * 640 + 576 + jo * 2) = (_Float16)pv;
                if (c == 0) out[((size_t)(B0 + bo) * TSTEPS + t) * 8 + jo] = pv;
            }
        }
        __syncthreads();  // B10
    }
}

// ------------------------- launch -------------------------
extern "C" void kernel_launch(void* const* d_in, const int* in_sizes, int n_in,
                              void* d_out, int out_size, void* d_ws, size_t ws_size,
                              hipStream_t stream) {
    if (ws_size < WS_NEED) return;

    const float* x_cv = (const float*)d_in[0];
    const float* pv_init = (const float*)d_in[1];
    const int* scen = (const int*)d_in[2];
    const float* embt = (const float*)d_in[3];
    const float* Wih0 = (const float*)d_in[4];
    const float* Whh0 = (const float*)d_in[5];
    const float* bih0 = (const float*)d_in[6];
    const float* bhh0 = (const float*)d_in[7];
    const float* Wih1 = (const float*)d_in[8];
    const float* Whh1 = (const float*)d_in[9];
    const float* bih1 = (const float*)d_in[10];
    const float* bhh1 = (const float*)d_in[11];
    const float* fc1w = (const float*)d_in[12];
    const float* fc1b = (const float*)d_in[13];
    const float* fc2w = (const float*)d_in[14];
    const float* fc2b = (const float*)d_in[15];

    char* ws = (char*)d_ws;

    prep_w<<<420, 256, 0, stream>>>(Wih0, Whh0, Wih1, Whh1, ws);

    lstm_main<<<256, 512, 0, stream>>>(x_cv, pv_init, scen, embt, Wih0, bih0, bhh0,
                                       bih1, bhh1, fc1w, fc1b, fc2w, fc2b, ws,
                                       (float*)d_out);
}